// Round 5
// baseline (266.180 us; speedup 1.0000x reference)
//
#include <hip/hip_runtime.h>
#include <hip/hip_bf16.h>

// Fixed-capacity buckets: bucket(d) = d >> 8; bucket b's edge region is
// [b*cap, b*cap + count[b]). No global compaction needed — the gathers only
// consume per-node rowstart/cnt. cap = mean + ~10 sigma; overflow edges are
// dropped defensively (never triggers: Poisson(4096), cap ~ mu+8sigma).

#define MAXBUCK 512   // supports N <= 131072
#define CURSTRIDE 16  // pad cursors to 64B lines: kills same-line atomic contention

typedef unsigned int uint32;

__device__ __forceinline__ void fma4(float4& a, float s, const float4& w) {
    a.x = fmaf(s, w.x, a.x); a.y = fmaf(s, w.y, a.y);
    a.z = fmaf(s, w.z, a.z); a.w = fmaf(s, w.w, a.w);
}
// round-to-nearest-even fp32 -> bf16 (16-bit result)
__device__ __forceinline__ uint32 bf16rn(float f) {
    uint32 u = __float_as_uint(f);
    return (u + 0x7fffu + ((u >> 16) & 1u)) >> 16;
}
__device__ __forceinline__ float bflo(uint32 v) { return __uint_as_float(v << 16); }
__device__ __forceinline__ float bfhi(uint32 v) { return __uint_as_float(v & 0xffff0000u); }

// ---------------- bin edges into fixed bucket regions (packed uint32) ----------------
// 4096 edges/block at 1024 threads (R2: 16 waves/block -> 6.1 waves/SIMD).
// Per-block LDS hist + one contiguous reservation per bucket keeps writes
// line-dense; global cursors 64B-strided so reservation atomics never share a
// line. Cursors are ZERO-based counts (R5: init via hipMemsetAsync, no initcur
// kernel); absolute base = b*cap added here. pack = src | (dst&255)<<24.
__global__ __launch_bounds__(1024) void k_bin(const int* __restrict__ src,
                                              const int* __restrict__ dst, int E,
                                              int nbuck, int cap,
                                              int* __restrict__ cursor,
                                              uint32* __restrict__ pairs) {
    __shared__ int hist[MAXBUCK];
    __shared__ int base_l[MAXBUCK];
    __shared__ int cur[MAXBUCK];
    int t = threadIdx.x;
    int e0 = blockIdx.x * 4096;
    for (int i = t; i < MAXBUCK; i += 1024) { hist[i] = 0; cur[i] = 0; }
    __syncthreads();
    for (int i = t; i < 4096; i += 1024) {
        int e = e0 + i;
        if (e < E) atomicAdd(&hist[dst[e] >> 8], 1);
    }
    __syncthreads();
    for (int i = t; i < nbuck; i += 1024)
        base_l[i] = hist[i] ? (i * cap + atomicAdd(&cursor[i * CURSTRIDE], hist[i])) : 0;
    __syncthreads();
    for (int i = t; i < 4096; i += 1024) {
        int e = e0 + i;
        if (e < E) {
            int d = dst[e];
            int b = d >> 8;
            int p = atomicAdd(&cur[b], 1);
            int idx = base_l[b] + p;
            if (idx < (b + 1) * cap)  // overflow guard (never fires for this input)
                pairs[idx] = (uint32)src[e] | ((uint32)(d & 255) << 24);
        }
    }
}

// ---------------- per-bucket CSR fill + cnt/rowstart/dinv ----------------
// one block per bucket at 1024 threads; scan guarded to t<256.
// bucket_cnt[b*CURSTRIDE] holds the bucket's edge COUNT (zero-based cursors).
__global__ __launch_bounds__(1024) void k_fill2(const uint32* __restrict__ pairs,
                                                const int* __restrict__ bucket_cnt,
                                                int cap, int N,
                                                int* __restrict__ srclist,
                                                int* __restrict__ rowstart,
                                                int* __restrict__ cnt,
                                                float* __restrict__ dinv) {
    __shared__ int hist[256];
    __shared__ int sh[256];
    __shared__ int rs_ex[256];
    __shared__ int cur[256];
    int b = blockIdx.x;
    int t = threadIdx.x;
    int start = b * cap;
    int end = start + min(bucket_cnt[b * CURSTRIDE], cap);
    int node0 = b << 8;

    if (t < 256) { hist[t] = 0; cur[t] = 0; }
    __syncthreads();
    for (int e = start + t; e < end; e += 1024)
        atomicAdd(&hist[pairs[e] >> 24], 1);
    __syncthreads();
    int v = 0;
    if (t < 256) { v = hist[t]; sh[t] = v; }
    __syncthreads();
    for (int off = 1; off < 256; off <<= 1) {
        int tmp = 0;
        if (t < 256 && t >= off) tmp = sh[t - off];
        __syncthreads();
        if (t < 256) sh[t] += tmp;
        __syncthreads();
    }
    if (t < 256) {
        rs_ex[t] = sh[t] - v;
        int node = node0 + t;
        if (node < N) {
            rowstart[node] = start + rs_ex[t];
            cnt[node] = v;
            dinv[node] = rsqrtf((float)(v + 1));
        }
    }
    __syncthreads();
    for (int e = start + t; e < end; e += 1024) {
        uint32 pr = pairs[e];
        int dl = pr >> 24;
        int p = atomicAdd(&cur[dl], 1);
        srclist[start + rs_ex[dl] + p] = (int)(pr & 0x00FFFFFFu);
    }
}

// ---------------- layer 1 GEMM: h1b = bf16((x @ W1) * dinv) ----------------
// 32 nodes/block; thread = 2 nodes x 4 cols. unroll 4 (R7: full unroll -> spill).
__global__ __launch_bounds__(256) void k_gemm1(const float* __restrict__ x,
                                               const float* __restrict__ W1,
                                               const float* __restrict__ dinv,
                                               uint32* __restrict__ h1b, int n) {
    __shared__ float W1s[128 * 64];   // 32 KB
    __shared__ float xs[32][132];     // padded
    int t = threadIdx.x;
    const float4* W1v = (const float4*)W1;
    float4* W1sv = (float4*)W1s;
    for (int i = t; i < 2048; i += 256) W1sv[i] = W1v[i];
    int node0 = blockIdx.x * 32;
    const float4* xv = (const float4*)x;
    for (int i = t; i < 1024; i += 256) {
        int nl = i >> 5, kq = i & 31;
        int node = node0 + nl;
        float4 v = make_float4(0.f, 0.f, 0.f, 0.f);
        if (node < n) v = xv[(size_t)node * 32 + kq];
        *(float4*)&xs[nl][kq * 4] = v;
    }
    __syncthreads();

    int tx = t & 15;
    int ty = t >> 4;
    int na = ty * 2, nb = na + 1;
    float4 acc0 = make_float4(0.f, 0.f, 0.f, 0.f);
    float4 acc1 = make_float4(0.f, 0.f, 0.f, 0.f);
    const float4* W1sq = (const float4*)W1s;
#pragma unroll 4
    for (int kq = 0; kq < 32; kq++) {
        float4 xa = *(const float4*)&xs[na][kq * 4];
        float4 xb = *(const float4*)&xs[nb][kq * 4];
        float4 w0 = W1sq[(kq * 4 + 0) * 16 + tx];
        float4 w1 = W1sq[(kq * 4 + 1) * 16 + tx];
        float4 w2 = W1sq[(kq * 4 + 2) * 16 + tx];
        float4 w3 = W1sq[(kq * 4 + 3) * 16 + tx];
        fma4(acc0, xa.x, w0); fma4(acc0, xa.y, w1);
        fma4(acc0, xa.z, w2); fma4(acc0, xa.w, w3);
        fma4(acc1, xb.x, w0); fma4(acc1, xb.y, w1);
        fma4(acc1, xb.z, w2); fma4(acc1, xb.w, w3);
    }
    int nA = node0 + na, nB = node0 + nb;
    if (nA < n) {
        float di = dinv[nA];
        uint2 pk = make_uint2(bf16rn(acc0.x * di) | (bf16rn(acc0.y * di) << 16),
                              bf16rn(acc0.z * di) | (bf16rn(acc0.w * di) << 16));
        ((uint2*)h1b)[(size_t)nA * 16 + tx] = pk;  // row = 32 uints = 16 uint2
    }
    if (nB < n) {
        float di = dinv[nB];
        uint2 pk = make_uint2(bf16rn(acc1.x * di) | (bf16rn(acc1.y * di) << 16),
                              bf16rn(acc1.z * di) | (bf16rn(acc1.w * di) << 16));
        ((uint2*)h1b)[(size_t)nB * 16 + tx] = pk;
    }
}

// ------- L1 gather + finalize + GEMM2 — two nodes/wave, DIRECT index loads -----
// R5: __shfl(sidx,·) compiled to ds_bpermute (LDS pipe, own lgkmcnt wait) and
// forced a 4-level chain: rowstart -> sidx -> bpermute -> gather. Replaced with
// direct srclist[row + i] loads (i quarter-uniform -> 16-lane broadcast, L1-hit):
// 3-level chain, level 2 fully co-issued. Loop shapes/load counts = R4 verbatim
// (R10 lesson: don't over-issue clamped loads).
// QUARTER-wave (16 lanes x uint2 = 128B) reads one neighbor row.
__global__ __launch_bounds__(256) void k_gather_l1(const int* __restrict__ rowstart,
                                                   const int* __restrict__ cnt,
                                                   const int* __restrict__ srclist,
                                                   const uint32* __restrict__ h1b,
                                                   const float* __restrict__ dinv,
                                                   const float* __restrict__ b1,
                                                   const float* __restrict__ W2,
                                                   unsigned short* __restrict__ h2b, int n) {
    __shared__ __align__(16) float W2s[64 * 32];  // 8 KB, W2s[k*32+c] (conflict-free)
    __shared__ __align__(16) float hb[8][64];     // 2 KB, one row per node
    int t = threadIdx.x;
    {   // stage W2 via float4: 512 float4s, 2 per thread
        const float4* W2v = (const float4*)W2;
        float4* W2sv = (float4*)W2s;
        W2sv[t] = W2v[t];
        W2sv[t + 256] = W2v[t + 256];
    }
    int wid = t >> 6, lane = t & 63;
    int nodeA = blockIdx.x * 8 + wid * 2;
    int nodeB = nodeA + 1;
    bool validA = (nodeA < n), validB = (nodeB < n);
    int j = lane & 15, q = lane >> 4;

    // meta A+B co-issued (independent misses)
    int rowA = 0, mA = 0, rowB = 0, mB = 0;
    float diA = 0.0f, diB = 0.0f;
    uint2 svA = make_uint2(0u, 0u), svB = make_uint2(0u, 0u);
    const uint2* h1v = (const uint2*)h1b;
    if (validA) { rowA = rowstart[nodeA]; mA = cnt[nodeA]; diA = dinv[nodeA];
                  svA = h1v[(size_t)nodeA * 16 + j]; }
    if (validB) { rowB = rowstart[nodeB]; mB = cnt[nodeB]; diB = dinv[nodeB];
                  svB = h1v[(size_t)nodeB * 16 + j]; }
    int mA0 = min(64, mA), mB0 = min(64, mB);  // first-batch sizes (wave-uniform)
    const int* slA = srclist + rowA;
    const int* slB = srclist + rowB;

    float aA0 = 0.f, aA1 = 0.f, aA2 = 0.f, aA3 = 0.f;
    float aB0 = 0.f, aB1 = 0.f, aB2 = 0.f, aB3 = 0.f;
    int jjA = 0, jjB = 0;
    // merged-16: 16 rows of A + 16 rows of B, 8 row loads in flight
    for (; jjA + 16 <= mA0 && jjB + 16 <= mB0; jjA += 16, jjB += 16) {
        int sA0 = slA[jjA + q],      sA1 = slA[jjA + 4 + q];
        int sA2 = slA[jjA + 8 + q],  sA3 = slA[jjA + 12 + q];
        int sB0 = slB[jjB + q],      sB1 = slB[jjB + 4 + q];
        int sB2 = slB[jjB + 8 + q],  sB3 = slB[jjB + 12 + q];
        uint2 vA0 = h1v[(size_t)sA0 * 16 + j], vA1 = h1v[(size_t)sA1 * 16 + j];
        uint2 vA2 = h1v[(size_t)sA2 * 16 + j], vA3 = h1v[(size_t)sA3 * 16 + j];
        uint2 vB0 = h1v[(size_t)sB0 * 16 + j], vB1 = h1v[(size_t)sB1 * 16 + j];
        uint2 vB2 = h1v[(size_t)sB2 * 16 + j], vB3 = h1v[(size_t)sB3 * 16 + j];
        aA0 += (bflo(vA0.x) + bflo(vA1.x)) + (bflo(vA2.x) + bflo(vA3.x));
        aA1 += (bfhi(vA0.x) + bfhi(vA1.x)) + (bfhi(vA2.x) + bfhi(vA3.x));
        aA2 += (bflo(vA0.y) + bflo(vA1.y)) + (bflo(vA2.y) + bflo(vA3.y));
        aA3 += (bfhi(vA0.y) + bfhi(vA1.y)) + (bfhi(vA2.y) + bfhi(vA3.y));
        aB0 += (bflo(vB0.x) + bflo(vB1.x)) + (bflo(vB2.x) + bflo(vB3.x));
        aB1 += (bfhi(vB0.x) + bfhi(vB1.x)) + (bfhi(vB2.x) + bfhi(vB3.x));
        aB2 += (bflo(vB0.y) + bflo(vB1.y)) + (bflo(vB2.y) + bflo(vB3.y));
        aB3 += (bfhi(vB0.y) + bfhi(vB1.y)) + (bfhi(vB2.y) + bfhi(vB3.y));
    }
    // merged-8: 8 rows each, 4 row loads in flight
    for (; jjA + 8 <= mA0 && jjB + 8 <= mB0; jjA += 8, jjB += 8) {
        int sA0 = slA[jjA + q], sA1 = slA[jjA + 4 + q];
        int sB0 = slB[jjB + q], sB1 = slB[jjB + 4 + q];
        uint2 vA0 = h1v[(size_t)sA0 * 16 + j], vA1 = h1v[(size_t)sA1 * 16 + j];
        uint2 vB0 = h1v[(size_t)sB0 * 16 + j], vB1 = h1v[(size_t)sB1 * 16 + j];
        aA0 += bflo(vA0.x) + bflo(vA1.x);
        aA1 += bfhi(vA0.x) + bfhi(vA1.x);
        aA2 += bflo(vA0.y) + bflo(vA1.y);
        aA3 += bfhi(vA0.y) + bfhi(vA1.y);
        aB0 += bflo(vB0.x) + bflo(vB1.x);
        aB1 += bfhi(vB0.x) + bfhi(vB1.x);
        aB2 += bflo(vB0.y) + bflo(vB1.y);
        aB3 += bfhi(vB0.y) + bfhi(vB1.y);
    }
    // drain A (first batch)
    for (; jjA + 8 <= mA0; jjA += 8) {
        int s0 = slA[jjA + q], s1 = slA[jjA + 4 + q];
        uint2 v0 = h1v[(size_t)s0 * 16 + j], v1 = h1v[(size_t)s1 * 16 + j];
        aA0 += bflo(v0.x) + bflo(v1.x);
        aA1 += bfhi(v0.x) + bfhi(v1.x);
        aA2 += bflo(v0.y) + bflo(v1.y);
        aA3 += bfhi(v0.y) + bfhi(v1.y);
    }
    for (; jjA < mA0; jjA += 4) {  // tail: clamp index, predicate the use (mA0 >= 1 here)
        int jidx = jjA + q;
        int s = slA[min(jidx, mA0 - 1)];
        uint2 v = h1v[(size_t)s * 16 + j];
        if (jidx < mA0) {
            aA0 += bflo(v.x); aA1 += bfhi(v.x);
            aA2 += bflo(v.y); aA3 += bfhi(v.y);
        }
    }
    // drain B (first batch)
    for (; jjB + 8 <= mB0; jjB += 8) {
        int s0 = slB[jjB + q], s1 = slB[jjB + 4 + q];
        uint2 v0 = h1v[(size_t)s0 * 16 + j], v1 = h1v[(size_t)s1 * 16 + j];
        aB0 += bflo(v0.x) + bflo(v1.x);
        aB1 += bfhi(v0.x) + bfhi(v1.x);
        aB2 += bflo(v0.y) + bflo(v1.y);
        aB3 += bfhi(v0.y) + bfhi(v1.y);
    }
    for (; jjB < mB0; jjB += 4) {
        int jidx = jjB + q;
        int s = slB[min(jidx, mB0 - 1)];
        uint2 v = h1v[(size_t)s * 16 + j];
        if (jidx < mB0) {
            aB0 += bflo(v.x); aB1 += bfhi(v.x);
            aB2 += bflo(v.y); aB3 += bfhi(v.y);
        }
    }
    // extra batches (degree > 64; essentially never for Poisson(16), kept for safety)
    for (int j0 = 64; j0 < mA; j0 += 64) {
        int m = min(64, mA - j0);
        const int* sl = slA + j0;
        int jj = 0;
        for (; jj + 8 <= m; jj += 8) {
            int s0 = sl[jj + q], s1 = sl[jj + 4 + q];
            uint2 v0 = h1v[(size_t)s0 * 16 + j], v1 = h1v[(size_t)s1 * 16 + j];
            aA0 += bflo(v0.x) + bflo(v1.x);
            aA1 += bfhi(v0.x) + bfhi(v1.x);
            aA2 += bflo(v0.y) + bflo(v1.y);
            aA3 += bfhi(v0.y) + bfhi(v1.y);
        }
        for (; jj < m; jj += 4) {
            int jidx = jj + q;
            int s = sl[min(jidx, m - 1)];
            uint2 v = h1v[(size_t)s * 16 + j];
            if (jidx < m) {
                aA0 += bflo(v.x); aA1 += bfhi(v.x);
                aA2 += bflo(v.y); aA3 += bfhi(v.y);
            }
        }
    }
    for (int j0 = 64; j0 < mB; j0 += 64) {
        int m = min(64, mB - j0);
        const int* sl = slB + j0;
        int jj = 0;
        for (; jj + 8 <= m; jj += 8) {
            int s0 = sl[jj + q], s1 = sl[jj + 4 + q];
            uint2 v0 = h1v[(size_t)s0 * 16 + j], v1 = h1v[(size_t)s1 * 16 + j];
            aB0 += bflo(v0.x) + bflo(v1.x);
            aB1 += bfhi(v0.x) + bfhi(v1.x);
            aB2 += bflo(v0.y) + bflo(v1.y);
            aB3 += bfhi(v0.y) + bfhi(v1.y);
        }
        for (; jj < m; jj += 4) {
            int jidx = jj + q;
            int s = sl[min(jidx, m - 1)];
            uint2 v = h1v[(size_t)s * 16 + j];
            if (jidx < m) {
                aB0 += bflo(v.x); aB1 += bfhi(v.x);
                aB2 += bflo(v.y); aB3 += bfhi(v.y);
            }
        }
    }

    // reduce + finalize
    aA0 += __shfl_xor(aA0, 16); aA0 += __shfl_xor(aA0, 32);
    aA1 += __shfl_xor(aA1, 16); aA1 += __shfl_xor(aA1, 32);
    aA2 += __shfl_xor(aA2, 16); aA2 += __shfl_xor(aA2, 32);
    aA3 += __shfl_xor(aA3, 16); aA3 += __shfl_xor(aA3, 32);
    aB0 += __shfl_xor(aB0, 16); aB0 += __shfl_xor(aB0, 32);
    aB1 += __shfl_xor(aB1, 16); aB1 += __shfl_xor(aB1, 32);
    aB2 += __shfl_xor(aB2, 16); aB2 += __shfl_xor(aB2, 32);
    aB3 += __shfl_xor(aB3, 16); aB3 += __shfl_xor(aB3, 32);
    if (validA && q == 0) {
        float4 bq = ((const float4*)b1)[j];
        float4 hv;
        hv.x = fmaxf((aA0 + bflo(svA.x)) * diA + bq.x, 0.0f);
        hv.y = fmaxf((aA1 + bfhi(svA.x)) * diA + bq.y, 0.0f);
        hv.z = fmaxf((aA2 + bflo(svA.y)) * diA + bq.z, 0.0f);
        hv.w = fmaxf((aA3 + bfhi(svA.y)) * diA + bq.w, 0.0f);
        *(float4*)&hb[wid * 2][4 * j] = hv;
    }
    if (validB && q == 0) {
        float4 bq = ((const float4*)b1)[j];
        float4 hv;
        hv.x = fmaxf((aB0 + bflo(svB.x)) * diB + bq.x, 0.0f);
        hv.y = fmaxf((aB1 + bfhi(svB.x)) * diB + bq.y, 0.0f);
        hv.z = fmaxf((aB2 + bflo(svB.y)) * diB + bq.z, 0.0f);
        hv.w = fmaxf((aB3 + bfhi(svB.y)) * diB + bq.w, 0.0f);
        *(float4*)&hb[wid * 2 + 1][4 * j] = hv;
    }
    __syncthreads();  // covers W2s staging and hb writes
    // GEMM2 split-k: half h sums k = h*32..h*32+31 for output col c
    int c = lane & 31, half = lane >> 5;
    int k0 = half * 32;
    if (validA) {
        float s = 0.0f;
        const float4* hb4 = (const float4*)&hb[wid * 2][k0];
#pragma unroll
        for (int kk = 0; kk < 8; kk++) {
            float4 h4 = hb4[kk];              // ds_read_b128, wave-uniform addr
            int kb = k0 + kk * 4;
            s = fmaf(h4.x, W2s[(kb + 0) * 32 + c], s);
            s = fmaf(h4.y, W2s[(kb + 1) * 32 + c], s);
            s = fmaf(h4.z, W2s[(kb + 2) * 32 + c], s);
            s = fmaf(h4.w, W2s[(kb + 3) * 32 + c], s);
        }
        s += __shfl_xor(s, 32);
        if (half == 0) h2b[(size_t)nodeA * 32 + c] = (unsigned short)bf16rn(s * diA);
    }
    if (validB) {
        float s = 0.0f;
        const float4* hb4 = (const float4*)&hb[wid * 2 + 1][k0];
#pragma unroll
        for (int kk = 0; kk < 8; kk++) {
            float4 h4 = hb4[kk];
            int kb = k0 + kk * 4;
            s = fmaf(h4.x, W2s[(kb + 0) * 32 + c], s);
            s = fmaf(h4.y, W2s[(kb + 1) * 32 + c], s);
            s = fmaf(h4.z, W2s[(kb + 2) * 32 + c], s);
            s = fmaf(h4.w, W2s[(kb + 3) * 32 + c], s);
        }
        s += __shfl_xor(s, 32);
        if (half == 0) h2b[(size_t)nodeB * 32 + c] = (unsigned short)bf16rn(s * diB);
    }
}

// ------- L2 gather + finalize — two nodes/wave, DIRECT index loads -------------
// EIGHTH-wave (8 lanes x uint2 = 64B) reads one row; lane j holds cols 4j..4j+3.
__global__ __launch_bounds__(256) void k_gather_l2(const int* __restrict__ rowstart,
                                                   const int* __restrict__ cnt,
                                                   const int* __restrict__ srclist,
                                                   const uint32* __restrict__ h2b,
                                                   const float* __restrict__ dinv,
                                                   const float* __restrict__ b2v,
                                                   float* __restrict__ out, int n) {
    int t = threadIdx.x;
    int wid = t >> 6, lane = t & 63;
    int nodeA = blockIdx.x * 8 + wid * 2;
    if (nodeA >= n) return;  // whole wave exits together (B too)
    int nodeB = nodeA + 1;
    bool validB = (nodeB < n);
    int j = lane & 7, o = lane >> 3;

    int rowA = rowstart[nodeA], mA = cnt[nodeA];
    float diA = dinv[nodeA];
    int rowB = 0, mB = 0;
    float diB = 0.0f;
    const uint2* h2v = (const uint2*)h2b;
    uint2 svA = h2v[(size_t)nodeA * 8 + j];
    uint2 svB = make_uint2(0u, 0u);
    if (validB) { rowB = rowstart[nodeB]; mB = cnt[nodeB]; diB = dinv[nodeB];
                  svB = h2v[(size_t)nodeB * 8 + j]; }
    int mA0 = min(64, mA), mB0 = min(64, mB);
    const int* slA = srclist + rowA;
    const int* slB = srclist + rowB;

    float aA0 = 0.f, aA1 = 0.f, aA2 = 0.f, aA3 = 0.f;
    float aB0 = 0.f, aB1 = 0.f, aB2 = 0.f, aB3 = 0.f;
    int jjA = 0, jjB = 0;
    // merged-16: 16 rows each, 4 row loads in flight
    for (; jjA + 16 <= mA0 && jjB + 16 <= mB0; jjA += 16, jjB += 16) {
        int sA0 = slA[jjA + o], sA1 = slA[jjA + 8 + o];
        int sB0 = slB[jjB + o], sB1 = slB[jjB + 8 + o];
        uint2 vA0 = h2v[(size_t)sA0 * 8 + j], vA1 = h2v[(size_t)sA1 * 8 + j];
        uint2 vB0 = h2v[(size_t)sB0 * 8 + j], vB1 = h2v[(size_t)sB1 * 8 + j];
        aA0 += bflo(vA0.x) + bflo(vA1.x);
        aA1 += bfhi(vA0.x) + bfhi(vA1.x);
        aA2 += bflo(vA0.y) + bflo(vA1.y);
        aA3 += bfhi(vA0.y) + bfhi(vA1.y);
        aB0 += bflo(vB0.x) + bflo(vB1.x);
        aB1 += bfhi(vB0.x) + bfhi(vB1.x);
        aB2 += bflo(vB0.y) + bflo(vB1.y);
        aB3 += bfhi(vB0.y) + bfhi(vB1.y);
    }
    // merged-8: 8 rows each, 2 row loads in flight
    for (; jjA + 8 <= mA0 && jjB + 8 <= mB0; jjA += 8, jjB += 8) {
        int sA0 = slA[jjA + o];
        int sB0 = slB[jjB + o];
        uint2 vA0 = h2v[(size_t)sA0 * 8 + j];
        uint2 vB0 = h2v[(size_t)sB0 * 8 + j];
        aA0 += bflo(vA0.x); aA1 += bfhi(vA0.x);
        aA2 += bflo(vA0.y); aA3 += bfhi(vA0.y);
        aB0 += bflo(vB0.x); aB1 += bfhi(vB0.x);
        aB2 += bflo(vB0.y); aB3 += bfhi(vB0.y);
    }
    // drain A
    for (; jjA + 8 <= mA0; jjA += 8) {
        int s0 = slA[jjA + o];
        uint2 v0 = h2v[(size_t)s0 * 8 + j];
        aA0 += bflo(v0.x); aA1 += bfhi(v0.x);
        aA2 += bflo(v0.y); aA3 += bfhi(v0.y);
    }
    if (jjA < mA0) {
        int jidx = jjA + o;
        int s = slA[min(jidx, mA0 - 1)];
        uint2 v = h2v[(size_t)s * 8 + j];
        if (jidx < mA0) {
            aA0 += bflo(v.x); aA1 += bfhi(v.x);
            aA2 += bflo(v.y); aA3 += bfhi(v.y);
        }
    }
    // drain B
    for (; jjB + 8 <= mB0; jjB += 8) {
        int s0 = slB[jjB + o];
        uint2 v0 = h2v[(size_t)s0 * 8 + j];
        aB0 += bflo(v0.x); aB1 += bfhi(v0.x);
        aB2 += bflo(v0.y); aB3 += bfhi(v0.y);
    }
    if (jjB < mB0) {
        int jidx = jjB + o;
        int s = slB[min(jidx, mB0 - 1)];
        uint2 v = h2v[(size_t)s * 8 + j];
        if (jidx < mB0) {
            aB0 += bflo(v.x); aB1 += bfhi(v.x);
            aB2 += bflo(v.y); aB3 += bfhi(v.y);
        }
    }
    // extra batches (degree > 64; kept for safety)
    for (int j0 = 64; j0 < mA; j0 += 64) {
        int m = min(64, mA - j0);
        const int* sl = slA + j0;
        int jj = 0;
        for (; jj + 8 <= m; jj += 8) {
            int s0 = sl[jj + o];
            uint2 v0 = h2v[(size_t)s0 * 8 + j];
            aA0 += bflo(v0.x); aA1 += bfhi(v0.x);
            aA2 += bflo(v0.y); aA3 += bfhi(v0.y);
        }
        if (jj < m) {
            int jidx = jj + o;
            int s = sl[min(jidx, m - 1)];
            uint2 v = h2v[(size_t)s * 8 + j];
            if (jidx < m) {
                aA0 += bflo(v.x); aA1 += bfhi(v.x);
                aA2 += bflo(v.y); aA3 += bfhi(v.y);
            }
        }
    }
    for (int j0 = 64; j0 < mB; j0 += 64) {
        int m = min(64, mB - j0);
        const int* sl = slB + j0;
        int jj = 0;
        for (; jj + 8 <= m; jj += 8) {
            int s0 = sl[jj + o];
            uint2 v0 = h2v[(size_t)s0 * 8 + j];
            aB0 += bflo(v0.x); aB1 += bfhi(v0.x);
            aB2 += bflo(v0.y); aB3 += bfhi(v0.y);
        }
        if (jj < m) {
            int jidx = jj + o;
            int s = sl[min(jidx, m - 1)];
            uint2 v = h2v[(size_t)s * 8 + j];
            if (jidx < m) {
                aB0 += bflo(v.x); aB1 += bfhi(v.x);
                aB2 += bflo(v.y); aB3 += bfhi(v.y);
            }
        }
    }

    aA0 += __shfl_xor(aA0, 8); aA0 += __shfl_xor(aA0, 16); aA0 += __shfl_xor(aA0, 32);
    aA1 += __shfl_xor(aA1, 8); aA1 += __shfl_xor(aA1, 16); aA1 += __shfl_xor(aA1, 32);
    aA2 += __shfl_xor(aA2, 8); aA2 += __shfl_xor(aA2, 16); aA2 += __shfl_xor(aA2, 32);
    aA3 += __shfl_xor(aA3, 8); aA3 += __shfl_xor(aA3, 16); aA3 += __shfl_xor(aA3, 32);
    aB0 += __shfl_xor(aB0, 8); aB0 += __shfl_xor(aB0, 16); aB0 += __shfl_xor(aB0, 32);
    aB1 += __shfl_xor(aB1, 8); aB1 += __shfl_xor(aB1, 16); aB1 += __shfl_xor(aB1, 32);
    aB2 += __shfl_xor(aB2, 8); aB2 += __shfl_xor(aB2, 16); aB2 += __shfl_xor(aB2, 32);
    aB3 += __shfl_xor(aB3, 8); aB3 += __shfl_xor(aB3, 16); aB3 += __shfl_xor(aB3, 32);
    if (o == 0) {
        float4 bq = ((const float4*)b2v)[j];
        float4 ov;
        ov.x = (aA0 + bflo(svA.x)) * diA + bq.x;
        ov.y = (aA1 + bfhi(svA.x)) * diA + bq.y;
        ov.z = (aA2 + bflo(svA.y)) * diA + bq.z;
        ov.w = (aA3 + bfhi(svA.y)) * diA + bq.w;
        ((float4*)out)[(size_t)nodeA * 8 + j] = ov;
        if (validB) {
            float4 ob;
            ob.x = (aB0 + bflo(svB.x)) * diB + bq.x;
            ob.y = (aB1 + bfhi(svB.x)) * diB + bq.y;
            ob.z = (aB2 + bflo(svB.y)) * diB + bq.z;
            ob.w = (aB3 + bfhi(svB.y)) * diB + bq.w;
            ((float4*)out)[(size_t)nodeB * 8 + j] = ob;
        }
    }
}

extern "C" void kernel_launch(void* const* d_in, const int* in_sizes, int n_in,
                              void* d_out, int out_size, void* d_ws, size_t ws_size,
                              hipStream_t stream) {
    const float* x  = (const float*)d_in[0];
    const int*   ei = (const int*)d_in[1];
    const float* W1 = (const float*)d_in[2];
    const float* b1 = (const float*)d_in[3];
    const float* W2 = (const float*)d_in[4];
    const float* b2 = (const float*)d_in[5];
    float* out = (float*)d_out;

    const int N = in_sizes[0] / 128;  // 100000
    const int E = in_sizes[1] / 2;    // 1600000
    const int* src = ei;
    const int* dst = ei + E;
    const int nbuck = (N + 255) >> 8;  // 391

    // per-bucket capacity: mean + mean/8 + 256, rounded up to 64 (~mu+10sigma)
    int mean = (E + nbuck - 1) / nbuck;
    int cap = (mean + (mean >> 3) + 256 + 63) & ~63;     // 4864 for this input
    size_t region = (size_t)nbuck * cap;                 // ~1.9M entries, 7.6 MB

    char* p = (char*)d_ws;
    uint32* pairs      = (uint32*)p;    p += region * 4;          // 7.6 MB
    int* srclist       = (int*)p;       p += region * 4;          // 7.6 MB
    uint32* h1b        = (uint32*)p;    p += (size_t)N * 64 * 2;  // 12.8 MB
    uint32* h2b        = (uint32*)p;    p += (size_t)N * 32 * 2;  // 6.4 MB
    int* cursor        = (int*)p;       p += MAXBUCK * CURSTRIDE * 4;  // 32 KB
    int* rowstart      = (int*)p;       p += (size_t)N * 4;
    int* cnt           = (int*)p;       p += (size_t)N * 4;
    float* dinv        = (float*)p;     p += (size_t)N * 4;       // total ~36 MB

    // zero-based per-bucket cursors (replaces k_initcur launch)
    hipMemsetAsync(cursor, 0, (size_t)nbuck * CURSTRIDE * 4, stream);
    k_bin<<<(E + 4095) / 4096, 1024, 0, stream>>>(src, dst, E, nbuck, cap, cursor, pairs);
    k_fill2<<<nbuck, 1024, 0, stream>>>(pairs, cursor, cap, N, srclist, rowstart, cnt, dinv);

    k_gemm1<<<(N + 31) / 32, 256, 0, stream>>>(x, W1, dinv, h1b, N);
    k_gather_l1<<<(N + 7) / 8, 256, 0, stream>>>(rowstart, cnt, srclist, h1b, dinv,
                                                 b1, W2, (unsigned short*)h2b, N);
    k_gather_l2<<<(N + 7) / 8, 256, 0, stream>>>(rowstart, cnt, srclist, h2b, dinv,
                                                 b2, out, N);
}

// Round 6
// 234.299 us; speedup vs baseline: 1.1361x; 1.1361x over previous
//
#include <hip/hip_runtime.h>
#include <hip/hip_bf16.h>

// Fixed-capacity buckets: bucket(d) = d >> 8; bucket b's edge region is
// [b*cap, b*cap + count[b]). No global compaction needed — the gathers only
// consume per-node rowstart/cnt. cap = mean + ~10 sigma; overflow edges are
// dropped defensively (never triggers: Poisson(4096), cap ~ mu+8sigma).

#define MAXBUCK 512   // supports N <= 131072
#define CURSTRIDE 16  // pad cursors to 64B lines: kills same-line atomic contention

typedef unsigned int uint32;

__device__ __forceinline__ void fma4(float4& a, float s, const float4& w) {
    a.x = fmaf(s, w.x, a.x); a.y = fmaf(s, w.y, a.y);
    a.z = fmaf(s, w.z, a.z); a.w = fmaf(s, w.w, a.w);
}
// round-to-nearest-even fp32 -> bf16 (16-bit result)
__device__ __forceinline__ uint32 bf16rn(float f) {
    uint32 u = __float_as_uint(f);
    return (u + 0x7fffu + ((u >> 16) & 1u)) >> 16;
}
__device__ __forceinline__ float bflo(uint32 v) { return __uint_as_float(v << 16); }
__device__ __forceinline__ float bfhi(uint32 v) { return __uint_as_float(v & 0xffff0000u); }

// ---------------- bin edges into fixed bucket regions (packed uint32) ----------------
// 4096 edges/block at 1024 threads. Per-block LDS hist + one contiguous
// reservation per bucket keeps writes line-dense; global cursors 64B-strided.
// Cursors are ZERO-based counts (init via hipMemsetAsync); absolute base =
// b*cap added here. R6: dst tile staged in LDS during hist pass — scatter pass
// re-reads from LDS instead of a second dependent global load.
// pack = src | (dst&255)<<24 (N < 2^24).
__global__ __launch_bounds__(1024) void k_bin(const int* __restrict__ src,
                                              const int* __restrict__ dst, int E,
                                              int nbuck, int cap,
                                              int* __restrict__ cursor,
                                              uint32* __restrict__ pairs) {
    __shared__ int hist[MAXBUCK];
    __shared__ int base_l[MAXBUCK];
    __shared__ int cur[MAXBUCK];
    __shared__ int dloc[4096];  // 16 KB: dst tile (2 blocks/CU -> 44 KB total, ok)
    int t = threadIdx.x;
    int e0 = blockIdx.x * 4096;
    for (int i = t; i < MAXBUCK; i += 1024) { hist[i] = 0; cur[i] = 0; }
    __syncthreads();
    for (int i = t; i < 4096; i += 1024) {
        int e = e0 + i;
        if (e < E) {
            int d = dst[e];
            dloc[i] = d;
            atomicAdd(&hist[d >> 8], 1);
        }
    }
    __syncthreads();
    for (int i = t; i < nbuck; i += 1024)
        base_l[i] = hist[i] ? (i * cap + atomicAdd(&cursor[i * CURSTRIDE], hist[i])) : 0;
    __syncthreads();
    for (int i = t; i < 4096; i += 1024) {
        int e = e0 + i;
        if (e < E) {
            int d = dloc[i];
            int b = d >> 8;
            int p = atomicAdd(&cur[b], 1);
            int idx = base_l[b] + p;
            if (idx < (b + 1) * cap)  // overflow guard (never fires for this input)
                pairs[idx] = (uint32)src[e] | ((uint32)(d & 255) << 24);
        }
    }
}

// ---------------- per-bucket CSR fill + cnt/rowstart/dinv ----------------
// one block per bucket at 1024 threads; scan guarded to t<256.
// bucket_cnt[b*CURSTRIDE] holds the bucket's edge COUNT (zero-based cursors).
__global__ __launch_bounds__(1024) void k_fill2(const uint32* __restrict__ pairs,
                                                const int* __restrict__ bucket_cnt,
                                                int cap, int N,
                                                int* __restrict__ srclist,
                                                int* __restrict__ rowstart,
                                                int* __restrict__ cnt,
                                                float* __restrict__ dinv) {
    __shared__ int hist[256];
    __shared__ int sh[256];
    __shared__ int rs_ex[256];
    __shared__ int cur[256];
    int b = blockIdx.x;
    int t = threadIdx.x;
    int start = b * cap;
    int end = start + min(bucket_cnt[b * CURSTRIDE], cap);
    int node0 = b << 8;

    if (t < 256) { hist[t] = 0; cur[t] = 0; }
    __syncthreads();
    for (int e = start + t; e < end; e += 1024)
        atomicAdd(&hist[pairs[e] >> 24], 1);
    __syncthreads();
    int v = 0;
    if (t < 256) { v = hist[t]; sh[t] = v; }
    __syncthreads();
    for (int off = 1; off < 256; off <<= 1) {
        int tmp = 0;
        if (t < 256 && t >= off) tmp = sh[t - off];
        __syncthreads();
        if (t < 256) sh[t] += tmp;
        __syncthreads();
    }
    if (t < 256) {
        rs_ex[t] = sh[t] - v;
        int node = node0 + t;
        if (node < N) {
            rowstart[node] = start + rs_ex[t];
            cnt[node] = v;
            dinv[node] = rsqrtf((float)(v + 1));
        }
    }
    __syncthreads();
    for (int e = start + t; e < end; e += 1024) {
        uint32 pr = pairs[e];
        int dl = pr >> 24;
        int p = atomicAdd(&cur[dl], 1);
        srclist[start + rs_ex[dl] + p] = (int)(pr & 0x00FFFFFFu);
    }
}

// ---------------- layer 1 GEMM: h1b = bf16((x @ W1) * dinv) ----------------
// 32 nodes/block; thread = 2 nodes x 4 cols. R6: k split in two phases
// (k 0..63 | 64..127) -> LDS 48.9 KB -> 24.7 KB, 3 -> 6 blocks/CU (37.5 -> 75%
// occupancy) so staging latency overlaps across blocks. FMA order unchanged
// (kq 0..15 then 16..31 == original kq 0..31) -> bit-identical results.
__global__ __launch_bounds__(256) void k_gemm1(const float* __restrict__ x,
                                               const float* __restrict__ W1,
                                               const float* __restrict__ dinv,
                                               uint32* __restrict__ h1b, int n) {
    __shared__ float W1s[64 * 64];    // 16 KB: half of W1 (64 k-rows x 64 cols)
    __shared__ float xs[32][68];      // 8.7 KB: 32 nodes x 64 k (padded; per-wave
                                      // xa rows land on banks 0/8/16/24 -> clean)
    int t = threadIdx.x;
    int node0 = blockIdx.x * 32;
    int tx = t & 15;
    int ty = t >> 4;
    int na = ty * 2, nb = na + 1;
    float4 acc0 = make_float4(0.f, 0.f, 0.f, 0.f);
    float4 acc1 = make_float4(0.f, 0.f, 0.f, 0.f);
    const float4* W1v = (const float4*)W1;   // 2048 float4s total
    const float4* xv = (const float4*)x;
    float4* W1sv = (float4*)W1s;
    const float4* W1sq = (const float4*)W1s;

#pragma unroll 1
    for (int ph = 0; ph < 2; ph++) {
        __syncthreads();  // protect previous phase's LDS reads (no-op cost at ph=0)
        // stage W1 k-rows [ph*64, ph*64+64): 1024 float4s, 4/thread
        for (int i = t; i < 1024; i += 256) W1sv[i] = W1v[ph * 1024 + i];
        // stage x cols [ph*64, ph*64+64) for 32 nodes: 512 float4s, 2/thread
        for (int i = t; i < 512; i += 256) {
            int nl = i >> 4, kq4 = i & 15;
            int node = node0 + nl;
            float4 v = make_float4(0.f, 0.f, 0.f, 0.f);
            if (node < n) v = xv[(size_t)node * 32 + ph * 16 + kq4];
            *(float4*)&xs[nl][kq4 * 4] = v;
        }
        __syncthreads();
#pragma unroll 4
        for (int kq = 0; kq < 16; kq++) {
            float4 xa = *(const float4*)&xs[na][kq * 4];
            float4 xb = *(const float4*)&xs[nb][kq * 4];
            float4 w0 = W1sq[(kq * 4 + 0) * 16 + tx];
            float4 w1 = W1sq[(kq * 4 + 1) * 16 + tx];
            float4 w2 = W1sq[(kq * 4 + 2) * 16 + tx];
            float4 w3 = W1sq[(kq * 4 + 3) * 16 + tx];
            fma4(acc0, xa.x, w0); fma4(acc0, xa.y, w1);
            fma4(acc0, xa.z, w2); fma4(acc0, xa.w, w3);
            fma4(acc1, xb.x, w0); fma4(acc1, xb.y, w1);
            fma4(acc1, xb.z, w2); fma4(acc1, xb.w, w3);
        }
    }
    int nA = node0 + na, nB = node0 + nb;
    if (nA < n) {
        float di = dinv[nA];
        uint2 pk = make_uint2(bf16rn(acc0.x * di) | (bf16rn(acc0.y * di) << 16),
                              bf16rn(acc0.z * di) | (bf16rn(acc0.w * di) << 16));
        ((uint2*)h1b)[(size_t)nA * 16 + tx] = pk;  // row = 32 uints = 16 uint2
    }
    if (nB < n) {
        float di = dinv[nB];
        uint2 pk = make_uint2(bf16rn(acc1.x * di) | (bf16rn(acc1.y * di) << 16),
                              bf16rn(acc1.z * di) | (bf16rn(acc1.w * di) << 16));
        ((uint2*)h1b)[(size_t)nB * 16 + tx] = pk;
    }
}

// ------- L1 gather + finalize + GEMM2 — R4 structure VERBATIM (proven 52.5us) --
// Two nodes/wave: meta A+B co-issued, sidx A+B co-issued (one vector load each,
// then cheap shfl broadcast — R5 lesson: do NOT replace shfl with per-iter
// global index loads), gather row-loads merged (merged-16: 8 in flight).
// QUARTER-wave (16 lanes x uint2 = 128B) reads one neighbor row.
__global__ __launch_bounds__(256) void k_gather_l1(const int* __restrict__ rowstart,
                                                   const int* __restrict__ cnt,
                                                   const int* __restrict__ srclist,
                                                   const uint32* __restrict__ h1b,
                                                   const float* __restrict__ dinv,
                                                   const float* __restrict__ b1,
                                                   const float* __restrict__ W2,
                                                   unsigned short* __restrict__ h2b, int n) {
    __shared__ __align__(16) float W2s[64 * 32];  // 8 KB, W2s[k*32+c] (conflict-free)
    __shared__ __align__(16) float hb[8][64];     // 2 KB, one row per node
    int t = threadIdx.x;
    {   // stage W2 via float4: 512 float4s, 2 per thread
        const float4* W2v = (const float4*)W2;
        float4* W2sv = (float4*)W2s;
        W2sv[t] = W2v[t];
        W2sv[t + 256] = W2v[t + 256];
    }
    int wid = t >> 6, lane = t & 63;
    int nodeA = blockIdx.x * 8 + wid * 2;
    int nodeB = nodeA + 1;
    bool validA = (nodeA < n), validB = (nodeB < n);
    int j = lane & 15, q = lane >> 4;

    // meta A+B co-issued (independent misses)
    int rowA = 0, mA = 0, rowB = 0, mB = 0;
    float diA = 0.0f, diB = 0.0f;
    uint2 svA = make_uint2(0u, 0u), svB = make_uint2(0u, 0u);
    const uint2* h1v = (const uint2*)h1b;
    if (validA) { rowA = rowstart[nodeA]; mA = cnt[nodeA]; diA = dinv[nodeA];
                  svA = h1v[(size_t)nodeA * 16 + j]; }
    if (validB) { rowB = rowstart[nodeB]; mB = cnt[nodeB]; diB = dinv[nodeB];
                  svB = h1v[(size_t)nodeB * 16 + j]; }
    int mA0 = min(64, mA), mB0 = min(64, mB);  // first-batch sizes (wave-uniform)
    // srclist A+B co-issued
    int sidxA = (lane < mA0) ? srclist[rowA + lane] : 0;
    int sidxB = (lane < mB0) ? srclist[rowB + lane] : 0;

    float aA0 = 0.f, aA1 = 0.f, aA2 = 0.f, aA3 = 0.f;
    float aB0 = 0.f, aB1 = 0.f, aB2 = 0.f, aB3 = 0.f;
    int jjA = 0, jjB = 0;
    // merged-16: 16 rows of A + 16 rows of B, 8 row loads in flight
    for (; jjA + 16 <= mA0 && jjB + 16 <= mB0; jjA += 16, jjB += 16) {
        int sA0 = __shfl(sidxA, jjA + q),      sA1 = __shfl(sidxA, jjA + 4 + q);
        int sA2 = __shfl(sidxA, jjA + 8 + q),  sA3 = __shfl(sidxA, jjA + 12 + q);
        int sB0 = __shfl(sidxB, jjB + q),      sB1 = __shfl(sidxB, jjB + 4 + q);
        int sB2 = __shfl(sidxB, jjB + 8 + q),  sB3 = __shfl(sidxB, jjB + 12 + q);
        uint2 vA0 = h1v[(size_t)sA0 * 16 + j], vA1 = h1v[(size_t)sA1 * 16 + j];
        uint2 vA2 = h1v[(size_t)sA2 * 16 + j], vA3 = h1v[(size_t)sA3 * 16 + j];
        uint2 vB0 = h1v[(size_t)sB0 * 16 + j], vB1 = h1v[(size_t)sB1 * 16 + j];
        uint2 vB2 = h1v[(size_t)sB2 * 16 + j], vB3 = h1v[(size_t)sB3 * 16 + j];
        aA0 += (bflo(vA0.x) + bflo(vA1.x)) + (bflo(vA2.x) + bflo(vA3.x));
        aA1 += (bfhi(vA0.x) + bfhi(vA1.x)) + (bfhi(vA2.x) + bfhi(vA3.x));
        aA2 += (bflo(vA0.y) + bflo(vA1.y)) + (bflo(vA2.y) + bflo(vA3.y));
        aA3 += (bfhi(vA0.y) + bfhi(vA1.y)) + (bfhi(vA2.y) + bfhi(vA3.y));
        aB0 += (bflo(vB0.x) + bflo(vB1.x)) + (bflo(vB2.x) + bflo(vB3.x));
        aB1 += (bfhi(vB0.x) + bfhi(vB1.x)) + (bfhi(vB2.x) + bfhi(vB3.x));
        aB2 += (bflo(vB0.y) + bflo(vB1.y)) + (bflo(vB2.y) + bflo(vB3.y));
        aB3 += (bfhi(vB0.y) + bfhi(vB1.y)) + (bfhi(vB2.y) + bfhi(vB3.y));
    }
    // merged-8: 8 rows each, 4 row loads in flight
    for (; jjA + 8 <= mA0 && jjB + 8 <= mB0; jjA += 8, jjB += 8) {
        int sA0 = __shfl(sidxA, jjA + q), sA1 = __shfl(sidxA, jjA + 4 + q);
        int sB0 = __shfl(sidxB, jjB + q), sB1 = __shfl(sidxB, jjB + 4 + q);
        uint2 vA0 = h1v[(size_t)sA0 * 16 + j], vA1 = h1v[(size_t)sA1 * 16 + j];
        uint2 vB0 = h1v[(size_t)sB0 * 16 + j], vB1 = h1v[(size_t)sB1 * 16 + j];
        aA0 += bflo(vA0.x) + bflo(vA1.x);
        aA1 += bfhi(vA0.x) + bfhi(vA1.x);
        aA2 += bflo(vA0.y) + bflo(vA1.y);
        aA3 += bfhi(vA0.y) + bfhi(vA1.y);
        aB0 += bflo(vB0.x) + bflo(vB1.x);
        aB1 += bfhi(vB0.x) + bfhi(vB1.x);
        aB2 += bflo(vB0.y) + bflo(vB1.y);
        aB3 += bfhi(vB0.y) + bfhi(vB1.y);
    }
    // drain A (first batch)
    for (; jjA + 8 <= mA0; jjA += 8) {
        int s0 = __shfl(sidxA, jjA + q), s1 = __shfl(sidxA, jjA + 4 + q);
        uint2 v0 = h1v[(size_t)s0 * 16 + j], v1 = h1v[(size_t)s1 * 16 + j];
        aA0 += bflo(v0.x) + bflo(v1.x);
        aA1 += bfhi(v0.x) + bfhi(v1.x);
        aA2 += bflo(v0.y) + bflo(v1.y);
        aA3 += bfhi(v0.y) + bfhi(v1.y);
    }
    for (; jjA < mA0; jjA += 4) {  // tail: clamp shfl lane, predicate the use
        int jidx = jjA + q;
        int s = __shfl(sidxA, min(jidx, mA0 - 1));
        uint2 v = h1v[(size_t)s * 16 + j];
        if (jidx < mA0) {
            aA0 += bflo(v.x); aA1 += bfhi(v.x);
            aA2 += bflo(v.y); aA3 += bfhi(v.y);
        }
    }
    // drain B (first batch)
    for (; jjB + 8 <= mB0; jjB += 8) {
        int s0 = __shfl(sidxB, jjB + q), s1 = __shfl(sidxB, jjB + 4 + q);
        uint2 v0 = h1v[(size_t)s0 * 16 + j], v1 = h1v[(size_t)s1 * 16 + j];
        aB0 += bflo(v0.x) + bflo(v1.x);
        aB1 += bfhi(v0.x) + bfhi(v1.x);
        aB2 += bflo(v0.y) + bflo(v1.y);
        aB3 += bfhi(v0.y) + bfhi(v1.y);
    }
    for (; jjB < mB0; jjB += 4) {
        int jidx = jjB + q;
        int s = __shfl(sidxB, min(jidx, mB0 - 1));
        uint2 v = h1v[(size_t)s * 16 + j];
        if (jidx < mB0) {
            aB0 += bflo(v.x); aB1 += bfhi(v.x);
            aB2 += bflo(v.y); aB3 += bfhi(v.y);
        }
    }
    // extra batches (degree > 64; essentially never for Poisson(16), kept for safety)
    for (int j0 = 64; j0 < mA; j0 += 64) {
        int m = min(64, mA - j0);
        int sb = (lane < m) ? srclist[rowA + j0 + lane] : 0;
        int jj = 0;
        for (; jj + 8 <= m; jj += 8) {
            int s0 = __shfl(sb, jj + q), s1 = __shfl(sb, jj + 4 + q);
            uint2 v0 = h1v[(size_t)s0 * 16 + j], v1 = h1v[(size_t)s1 * 16 + j];
            aA0 += bflo(v0.x) + bflo(v1.x);
            aA1 += bfhi(v0.x) + bfhi(v1.x);
            aA2 += bflo(v0.y) + bflo(v1.y);
            aA3 += bfhi(v0.y) + bfhi(v1.y);
        }
        for (; jj < m; jj += 4) {
            int jidx = jj + q;
            int s = __shfl(sb, min(jidx, m - 1));
            uint2 v = h1v[(size_t)s * 16 + j];
            if (jidx < m) {
                aA0 += bflo(v.x); aA1 += bfhi(v.x);
                aA2 += bflo(v.y); aA3 += bfhi(v.y);
            }
        }
    }
    for (int j0 = 64; j0 < mB; j0 += 64) {
        int m = min(64, mB - j0);
        int sb = (lane < m) ? srclist[rowB + j0 + lane] : 0;
        int jj = 0;
        for (; jj + 8 <= m; jj += 8) {
            int s0 = __shfl(sb, jj + q), s1 = __shfl(sb, jj + 4 + q);
            uint2 v0 = h1v[(size_t)s0 * 16 + j], v1 = h1v[(size_t)s1 * 16 + j];
            aB0 += bflo(v0.x) + bflo(v1.x);
            aB1 += bfhi(v0.x) + bfhi(v1.x);
            aB2 += bflo(v0.y) + bflo(v1.y);
            aB3 += bfhi(v0.y) + bfhi(v1.y);
        }
        for (; jj < m; jj += 4) {
            int jidx = jj + q;
            int s = __shfl(sb, min(jidx, m - 1));
            uint2 v = h1v[(size_t)s * 16 + j];
            if (jidx < m) {
                aB0 += bflo(v.x); aB1 += bfhi(v.x);
                aB2 += bflo(v.y); aB3 += bfhi(v.y);
            }
        }
    }

    // reduce + finalize
    aA0 += __shfl_xor(aA0, 16); aA0 += __shfl_xor(aA0, 32);
    aA1 += __shfl_xor(aA1, 16); aA1 += __shfl_xor(aA1, 32);
    aA2 += __shfl_xor(aA2, 16); aA2 += __shfl_xor(aA2, 32);
    aA3 += __shfl_xor(aA3, 16); aA3 += __shfl_xor(aA3, 32);
    aB0 += __shfl_xor(aB0, 16); aB0 += __shfl_xor(aB0, 32);
    aB1 += __shfl_xor(aB1, 16); aB1 += __shfl_xor(aB1, 32);
    aB2 += __shfl_xor(aB2, 16); aB2 += __shfl_xor(aB2, 32);
    aB3 += __shfl_xor(aB3, 16); aB3 += __shfl_xor(aB3, 32);
    if (validA && q == 0) {
        float4 bq = ((const float4*)b1)[j];
        float4 hv;
        hv.x = fmaxf((aA0 + bflo(svA.x)) * diA + bq.x, 0.0f);
        hv.y = fmaxf((aA1 + bfhi(svA.x)) * diA + bq.y, 0.0f);
        hv.z = fmaxf((aA2 + bflo(svA.y)) * diA + bq.z, 0.0f);
        hv.w = fmaxf((aA3 + bfhi(svA.y)) * diA + bq.w, 0.0f);
        *(float4*)&hb[wid * 2][4 * j] = hv;
    }
    if (validB && q == 0) {
        float4 bq = ((const float4*)b1)[j];
        float4 hv;
        hv.x = fmaxf((aB0 + bflo(svB.x)) * diB + bq.x, 0.0f);
        hv.y = fmaxf((aB1 + bfhi(svB.x)) * diB + bq.y, 0.0f);
        hv.z = fmaxf((aB2 + bflo(svB.y)) * diB + bq.z, 0.0f);
        hv.w = fmaxf((aB3 + bfhi(svB.y)) * diB + bq.w, 0.0f);
        *(float4*)&hb[wid * 2 + 1][4 * j] = hv;
    }
    __syncthreads();  // covers W2s staging and hb writes
    // GEMM2 split-k: half h sums k = h*32..h*32+31 for output col c
    int c = lane & 31, half = lane >> 5;
    int k0 = half * 32;
    if (validA) {
        float s = 0.0f;
        const float4* hb4 = (const float4*)&hb[wid * 2][k0];
#pragma unroll
        for (int kk = 0; kk < 8; kk++) {
            float4 h4 = hb4[kk];              // ds_read_b128, wave-uniform addr
            int kb = k0 + kk * 4;
            s = fmaf(h4.x, W2s[(kb + 0) * 32 + c], s);
            s = fmaf(h4.y, W2s[(kb + 1) * 32 + c], s);
            s = fmaf(h4.z, W2s[(kb + 2) * 32 + c], s);
            s = fmaf(h4.w, W2s[(kb + 3) * 32 + c], s);
        }
        s += __shfl_xor(s, 32);
        if (half == 0) h2b[(size_t)nodeA * 32 + c] = (unsigned short)bf16rn(s * diA);
    }
    if (validB) {
        float s = 0.0f;
        const float4* hb4 = (const float4*)&hb[wid * 2 + 1][k0];
#pragma unroll
        for (int kk = 0; kk < 8; kk++) {
            float4 h4 = hb4[kk];
            int kb = k0 + kk * 4;
            s = fmaf(h4.x, W2s[(kb + 0) * 32 + c], s);
            s = fmaf(h4.y, W2s[(kb + 1) * 32 + c], s);
            s = fmaf(h4.z, W2s[(kb + 2) * 32 + c], s);
            s = fmaf(h4.w, W2s[(kb + 3) * 32 + c], s);
        }
        s += __shfl_xor(s, 32);
        if (half == 0) h2b[(size_t)nodeB * 32 + c] = (unsigned short)bf16rn(s * diB);
    }
}

// ------- L2 gather + finalize — R4 structure VERBATIM, two nodes per wave -----
// EIGHTH-wave (8 lanes x uint2 = 64B) reads one row; lane j holds cols 4j..4j+3.
__global__ __launch_bounds__(256) void k_gather_l2(const int* __restrict__ rowstart,
                                                   const int* __restrict__ cnt,
                                                   const int* __restrict__ srclist,
                                                   const uint32* __restrict__ h2b,
                                                   const float* __restrict__ dinv,
                                                   const float* __restrict__ b2v,
                                                   float* __restrict__ out, int n) {
    int t = threadIdx.x;
    int wid = t >> 6, lane = t & 63;
    int nodeA = blockIdx.x * 8 + wid * 2;
    if (nodeA >= n) return;  // whole wave exits together (B too)
    int nodeB = nodeA + 1;
    bool validB = (nodeB < n);
    int j = lane & 7, o = lane >> 3;

    int rowA = rowstart[nodeA], mA = cnt[nodeA];
    float diA = dinv[nodeA];
    int rowB = 0, mB = 0;
    float diB = 0.0f;
    const uint2* h2v = (const uint2*)h2b;
    uint2 svA = h2v[(size_t)nodeA * 8 + j];
    uint2 svB = make_uint2(0u, 0u);
    if (validB) { rowB = rowstart[nodeB]; mB = cnt[nodeB]; diB = dinv[nodeB];
                  svB = h2v[(size_t)nodeB * 8 + j]; }
    int mA0 = min(64, mA), mB0 = min(64, mB);
    int sidxA = (lane < mA0) ? srclist[rowA + lane] : 0;
    int sidxB = (lane < mB0) ? srclist[rowB + lane] : 0;

    float aA0 = 0.f, aA1 = 0.f, aA2 = 0.f, aA3 = 0.f;
    float aB0 = 0.f, aB1 = 0.f, aB2 = 0.f, aB3 = 0.f;
    int jjA = 0, jjB = 0;
    // merged-16: 16 rows each, 4 row loads in flight
    for (; jjA + 16 <= mA0 && jjB + 16 <= mB0; jjA += 16, jjB += 16) {
        int sA0 = __shfl(sidxA, jjA + o), sA1 = __shfl(sidxA, jjA + 8 + o);
        int sB0 = __shfl(sidxB, jjB + o), sB1 = __shfl(sidxB, jjB + 8 + o);
        uint2 vA0 = h2v[(size_t)sA0 * 8 + j], vA1 = h2v[(size_t)sA1 * 8 + j];
        uint2 vB0 = h2v[(size_t)sB0 * 8 + j], vB1 = h2v[(size_t)sB1 * 8 + j];
        aA0 += bflo(vA0.x) + bflo(vA1.x);
        aA1 += bfhi(vA0.x) + bfhi(vA1.x);
        aA2 += bflo(vA0.y) + bflo(vA1.y);
        aA3 += bfhi(vA0.y) + bfhi(vA1.y);
        aB0 += bflo(vB0.x) + bflo(vB1.x);
        aB1 += bfhi(vB0.x) + bfhi(vB1.x);
        aB2 += bflo(vB0.y) + bflo(vB1.y);
        aB3 += bfhi(vB0.y) + bfhi(vB1.y);
    }
    // merged-8: 8 rows each, 2 row loads in flight
    for (; jjA + 8 <= mA0 && jjB + 8 <= mB0; jjA += 8, jjB += 8) {
        int sA0 = __shfl(sidxA, jjA + o);
        int sB0 = __shfl(sidxB, jjB + o);
        uint2 vA0 = h2v[(size_t)sA0 * 8 + j];
        uint2 vB0 = h2v[(size_t)sB0 * 8 + j];
        aA0 += bflo(vA0.x); aA1 += bfhi(vA0.x);
        aA2 += bflo(vA0.y); aA3 += bfhi(vA0.y);
        aB0 += bflo(vB0.x); aB1 += bfhi(vB0.x);
        aB2 += bflo(vB0.y); aB3 += bfhi(vB0.y);
    }
    // drain A
    for (; jjA + 8 <= mA0; jjA += 8) {
        int s0 = __shfl(sidxA, jjA + o);
        uint2 v0 = h2v[(size_t)s0 * 8 + j];
        aA0 += bflo(v0.x); aA1 += bfhi(v0.x);
        aA2 += bflo(v0.y); aA3 += bfhi(v0.y);
    }
    if (jjA < mA0) {
        int jidx = jjA + o;
        int s = __shfl(sidxA, min(jidx, mA0 - 1));
        uint2 v = h2v[(size_t)s * 8 + j];
        if (jidx < mA0) {
            aA0 += bflo(v.x); aA1 += bfhi(v.x);
            aA2 += bflo(v.y); aA3 += bfhi(v.y);
        }
    }
    // drain B
    for (; jjB + 8 <= mB0; jjB += 8) {
        int s0 = __shfl(sidxB, jjB + o);
        uint2 v0 = h2v[(size_t)s0 * 8 + j];
        aB0 += bflo(v0.x); aB1 += bfhi(v0.x);
        aB2 += bflo(v0.y); aB3 += bfhi(v0.y);
    }
    if (jjB < mB0) {
        int jidx = jjB + o;
        int s = __shfl(sidxB, min(jidx, mB0 - 1));
        uint2 v = h2v[(size_t)s * 8 + j];
        if (jidx < mB0) {
            aB0 += bflo(v.x); aB1 += bfhi(v.x);
            aB2 += bflo(v.y); aB3 += bfhi(v.y);
        }
    }
    // extra batches (degree > 64; kept for safety)
    for (int j0 = 64; j0 < mA; j0 += 64) {
        int m = min(64, mA - j0);
        int sb = (lane < m) ? srclist[rowA + j0 + lane] : 0;
        int jj = 0;
        for (; jj + 8 <= m; jj += 8) {
            int s0 = __shfl(sb, jj + o);
            uint2 v0 = h2v[(size_t)s0 * 8 + j];
            aA0 += bflo(v0.x); aA1 += bfhi(v0.x);
            aA2 += bflo(v0.y); aA3 += bfhi(v0.y);
        }
        if (jj < m) {
            int jidx = jj + o;
            int s = __shfl(sb, min(jidx, m - 1));
            uint2 v = h2v[(size_t)s * 8 + j];
            if (jidx < m) {
                aA0 += bflo(v.x); aA1 += bfhi(v.x);
                aA2 += bflo(v.y); aA3 += bfhi(v.y);
            }
        }
    }
    for (int j0 = 64; j0 < mB; j0 += 64) {
        int m = min(64, mB - j0);
        int sb = (lane < m) ? srclist[rowB + j0 + lane] : 0;
        int jj = 0;
        for (; jj + 8 <= m; jj += 8) {
            int s0 = __shfl(sb, jj + o);
            uint2 v0 = h2v[(size_t)s0 * 8 + j];
            aB0 += bflo(v0.x); aB1 += bfhi(v0.x);
            aB2 += bflo(v0.y); aB3 += bfhi(v0.y);
        }
        if (jj < m) {
            int jidx = jj + o;
            int s = __shfl(sb, min(jidx, m - 1));
            uint2 v = h2v[(size_t)s * 8 + j];
            if (jidx < m) {
                aB0 += bflo(v.x); aB1 += bfhi(v.x);
                aB2 += bflo(v.y); aB3 += bfhi(v.y);
            }
        }
    }

    aA0 += __shfl_xor(aA0, 8); aA0 += __shfl_xor(aA0, 16); aA0 += __shfl_xor(aA0, 32);
    aA1 += __shfl_xor(aA1, 8); aA1 += __shfl_xor(aA1, 16); aA1 += __shfl_xor(aA1, 32);
    aA2 += __shfl_xor(aA2, 8); aA2 += __shfl_xor(aA2, 16); aA2 += __shfl_xor(aA2, 32);
    aA3 += __shfl_xor(aA3, 8); aA3 += __shfl_xor(aA3, 16); aA3 += __shfl_xor(aA3, 32);
    aB0 += __shfl_xor(aB0, 8); aB0 += __shfl_xor(aB0, 16); aB0 += __shfl_xor(aB0, 32);
    aB1 += __shfl_xor(aB1, 8); aB1 += __shfl_xor(aB1, 16); aB1 += __shfl_xor(aB1, 32);
    aB2 += __shfl_xor(aB2, 8); aB2 += __shfl_xor(aB2, 16); aB2 += __shfl_xor(aB2, 32);
    aB3 += __shfl_xor(aB3, 8); aB3 += __shfl_xor(aB3, 16); aB3 += __shfl_xor(aB3, 32);
    if (o == 0) {
        float4 bq = ((const float4*)b2v)[j];
        float4 ov;
        ov.x = (aA0 + bflo(svA.x)) * diA + bq.x;
        ov.y = (aA1 + bfhi(svA.x)) * diA + bq.y;
        ov.z = (aA2 + bflo(svA.y)) * diA + bq.z;
        ov.w = (aA3 + bfhi(svA.y)) * diA + bq.w;
        ((float4*)out)[(size_t)nodeA * 8 + j] = ov;
        if (validB) {
            float4 ob;
            ob.x = (aB0 + bflo(svB.x)) * diB + bq.x;
            ob.y = (aB1 + bfhi(svB.x)) * diB + bq.y;
            ob.z = (aB2 + bflo(svB.y)) * diB + bq.z;
            ob.w = (aB3 + bfhi(svB.y)) * diB + bq.w;
            ((float4*)out)[(size_t)nodeB * 8 + j] = ob;
        }
    }
}

extern "C" void kernel_launch(void* const* d_in, const int* in_sizes, int n_in,
                              void* d_out, int out_size, void* d_ws, size_t ws_size,
                              hipStream_t stream) {
    const float* x  = (const float*)d_in[0];
    const int*   ei = (const int*)d_in[1];
    const float* W1 = (const float*)d_in[2];
    const float* b1 = (const float*)d_in[3];
    const float* W2 = (const float*)d_in[4];
    const float* b2 = (const float*)d_in[5];
    float* out = (float*)d_out;

    const int N = in_sizes[0] / 128;  // 100000
    const int E = in_sizes[1] / 2;    // 1600000
    const int* src = ei;
    const int* dst = ei + E;
    const int nbuck = (N + 255) >> 8;  // 391

    // per-bucket capacity: mean + mean/8 + 256, rounded up to 64 (~mu+10sigma)
    int mean = (E + nbuck - 1) / nbuck;
    int cap = (mean + (mean >> 3) + 256 + 63) & ~63;     // 4864 for this input
    size_t region = (size_t)nbuck * cap;                 // ~1.9M entries, 7.6 MB

    char* p = (char*)d_ws;
    uint32* pairs      = (uint32*)p;    p += region * 4;          // 7.6 MB
    int* srclist       = (int*)p;       p += region * 4;          // 7.6 MB
    uint32* h1b        = (uint32*)p;    p += (size_t)N * 64 * 2;  // 12.8 MB
    uint32* h2b        = (uint32*)p;    p += (size_t)N * 32 * 2;  // 6.4 MB
    int* cursor        = (int*)p;       p += MAXBUCK * CURSTRIDE * 4;  // 32 KB
    int* rowstart      = (int*)p;       p += (size_t)N * 4;
    int* cnt           = (int*)p;       p += (size_t)N * 4;
    float* dinv        = (float*)p;     p += (size_t)N * 4;       // total ~36 MB

    // zero-based per-bucket cursors (replaces k_initcur launch)
    hipMemsetAsync(cursor, 0, (size_t)nbuck * CURSTRIDE * 4, stream);
    k_bin<<<(E + 4095) / 4096, 1024, 0, stream>>>(src, dst, E, nbuck, cap, cursor, pairs);
    k_fill2<<<nbuck, 1024, 0, stream>>>(pairs, cursor, cap, N, srclist, rowstart, cnt, dinv);

    k_gemm1<<<(N + 31) / 32, 256, 0, stream>>>(x, W1, dinv, h1b, N);
    k_gather_l1<<<(N + 7) / 8, 256, 0, stream>>>(rowstart, cnt, srclist, h1b, dinv,
                                                 b1, W2, (unsigned short*)h2b, N);
    k_gather_l2<<<(N + 7) / 8, 256, 0, stream>>>(rowstart, cnt, srclist, h2b, dinv,
                                                 b2, out, N);
}